// Round 3
// baseline (632.145 us; speedup 1.0000x reference)
//
#include <hip/hip_runtime.h>
#include <hip/hip_bf16.h>
#include <stdint.h>

#define IN_F   4096
#define OUT_F  4096
#define M_TOT  8192   // 4 * 2048

typedef __bf16 bf16x8 __attribute__((ext_vector_type(8)));
typedef float  floatx4 __attribute__((ext_vector_type(4)));

__device__ __forceinline__ unsigned f2bf_bits(float f) {
    union { float f; uint32_t u; } v; v.f = f;
    uint32_t r = v.u + 0x7FFF + ((v.u >> 16) & 1);   // RNE
    return r >> 16;
}

__device__ __forceinline__ void gl_lds16(const void* g, void* l) {
    __builtin_amdgcn_global_load_lds(
        (const __attribute__((address_space(1))) void*)g,
        (__attribute__((address_space(3))) void*)l, 16, 0, 0);
}

// ---- W: packed int4 -> bf16, 4 packed ints (8 weights)/thread ----
__global__ void dequant_kernel(const int* __restrict__ packed,
                               const float* __restrict__ scales,
                               const float* __restrict__ offsets,
                               ushort* __restrict__ wb) {
    int i = blockIdx.x * 256 + threadIdx.x;
    int4 p = reinterpret_cast<const int4*>(packed)[i];
    int g = i >> 4;                                   // (8*i)/128
    float s = scales[g], off = offsets[g];
    uint4 ov;
    ov.x = f2bf_bits((float)(p.x & 0xF) * s + off) |
           (f2bf_bits((float)((p.x >> 4) & 0xF) * s + off) << 16);
    ov.y = f2bf_bits((float)(p.y & 0xF) * s + off) |
           (f2bf_bits((float)((p.y >> 4) & 0xF) * s + off) << 16);
    ov.z = f2bf_bits((float)(p.z & 0xF) * s + off) |
           (f2bf_bits((float)((p.z >> 4) & 0xF) * s + off) << 16);
    ov.w = f2bf_bits((float)(p.w & 0xF) * s + off) |
           (f2bf_bits((float)((p.w >> 4) & 0xF) * s + off) << 16);
    reinterpret_cast<uint4*>(wb)[i] = ov;
}

// ---- GEMM: C = A(fp32)[M_TOT][IN_F] * B(bf16)[OUT_F][IN_F]^T + bias ----
// A staged fp32 via global_load_lds (16 KB tile), converted to bf16 at
// fragment-read time. 128x128 tile, BK=32, 256 threads, 2x2 waves, 4x4 MFMA.
// A LDS swizzle: 8 chunks(16B)/row, logical l stored at p = l ^ (r&7).
// B LDS swizzle: 4 chunks/row, p = l ^ ((r>>1)&3)  (round-2, 0 conflicts).
__global__ void gemm_kernel(const float* __restrict__ A,    // fp32 [M_TOT][IN_F]
                            const ushort* __restrict__ B,   // bf16 [OUT_F][IN_F]
                            const float* __restrict__ bias,
                            float* __restrict__ C) {
    __shared__ __align__(16) float  Asf[128 * 32];   // 16 KB
    __shared__ __align__(16) ushort Bs[128 * 32];    // 8 KB

    const int tid  = threadIdx.x;
    const int wave = tid >> 6;
    const int lane = tid & 63;
    const int quad = lane >> 4;
    const int l16  = lane & 15;
    const int wm   = wave >> 1;
    const int wn   = wave & 1;

    const int bm = blockIdx.y;
    const int bn = blockIdx.x;

    // A staging: chunk c = i*256+tid ; r = i*32 + (tid>>3); p = tid&7;
    // logical chunk l = p ^ (r&7) — issue-independent.
    const int ar = tid >> 3;                       // 0..31
    const int al = (tid & 7) ^ (ar & 7);
    const float* gA0 = A + (size_t)(bm * 128 +  0 + ar) * IN_F + al * 4;
    const float* gA1 = A + (size_t)(bm * 128 + 32 + ar) * IN_F + al * 4;
    const float* gA2 = A + (size_t)(bm * 128 + 64 + ar) * IN_F + al * 4;
    const float* gA3 = A + (size_t)(bm * 128 + 96 + ar) * IN_F + al * 4;

    // B staging: chunk c = i*256+tid ; r = i*64 + (tid>>2); p = tid&3;
    // logical l = p ^ ((r>>1)&3) = (tid&3) ^ ((tid>>3)&3) — issue-independent.
    const int br = tid >> 2;                       // 0..63
    const int bl = (tid & 3) ^ ((tid >> 3) & 3);
    const ushort* gB0 = B + (size_t)(bn * 128 +  0 + br) * IN_F + bl * 8;
    const ushort* gB1 = B + (size_t)(bn * 128 + 64 + br) * IN_F + bl * 8;

    char* lA0 = (char*)Asf + 0 * 4096 + wave * 1024;
    char* lA1 = (char*)Asf + 1 * 4096 + wave * 1024;
    char* lA2 = (char*)Asf + 2 * 4096 + wave * 1024;
    char* lA3 = (char*)Asf + 3 * 4096 + wave * 1024;
    char* lB0 = (char*)Bs + 0 * 4096 + wave * 1024;
    char* lB1 = (char*)Bs + 1 * 4096 + wave * 1024;

    floatx4 acc[4][4] = {};

    const int arow = wm * 64 + l16;   // + mi*16 (mi*16 ≡ 0 mod 8 → swizzle mi-indep)
    const int brow = wn * 64 + l16;   // + ni*16
    const int aswz = l16 & 7;
    const int ac0  = ((2 * quad)     ^ aswz) * 4;   // physical float col, chunk j=0
    const int ac1  = ((2 * quad + 1) ^ aswz) * 4;   // chunk j=1
    const int koff = (quad ^ ((l16 >> 1) & 3)) * 8; // B read (round-2 swizzle)

    for (int k0 = 0; k0 < IN_F; k0 += 32) {
        gl_lds16(gA0, lA0); gl_lds16(gA1, lA1);
        gl_lds16(gA2, lA2); gl_lds16(gA3, lA3);
        gl_lds16(gB0, lB0); gl_lds16(gB1, lB1);
        gA0 += 32; gA1 += 32; gA2 += 32; gA3 += 32;
        gB0 += 32; gB1 += 32;
        __syncthreads();

        bf16x8 af[4], bfr[4];
#pragma unroll
        for (int mi = 0; mi < 4; ++mi) {
            const float* rowp = &Asf[(arow + mi * 16) * 32];
            float4 f0 = *reinterpret_cast<const float4*>(rowp + ac0);
            float4 f1 = *reinterpret_cast<const float4*>(rowp + ac1);
            bf16x8 v;
            v[0] = (__bf16)f0.x; v[1] = (__bf16)f0.y;
            v[2] = (__bf16)f0.z; v[3] = (__bf16)f0.w;
            v[4] = (__bf16)f1.x; v[5] = (__bf16)f1.y;
            v[6] = (__bf16)f1.z; v[7] = (__bf16)f1.w;
            af[mi] = v;
        }
#pragma unroll
        for (int ni = 0; ni < 4; ++ni)
            bfr[ni] = *reinterpret_cast<const bf16x8*>(&Bs[(brow + ni * 16) * 32 + koff]);

#pragma unroll
        for (int mi = 0; mi < 4; ++mi)
#pragma unroll
            for (int ni = 0; ni < 4; ++ni)
                acc[mi][ni] = __builtin_amdgcn_mfma_f32_16x16x32_bf16(
                    af[mi], bfr[ni], acc[mi][ni], 0, 0, 0);

        __syncthreads();
    }

    // epilogue: D lane mapping col = l16, row = quad*4 + r
    const float* biasp = bias + bn * 128 + wn * 64 + l16;
    float* Cp = C + (size_t)(bm * 128 + wm * 64 + quad * 4) * OUT_F + bn * 128 + wn * 64 + l16;
#pragma unroll
    for (int mi = 0; mi < 4; ++mi) {
#pragma unroll
        for (int ni = 0; ni < 4; ++ni) {
            float bv = biasp[ni * 16];
#pragma unroll
            for (int r = 0; r < 4; ++r)
                Cp[(size_t)(mi * 16 + r) * OUT_F + ni * 16] = acc[mi][ni][r] + bv;
        }
    }
}

extern "C" void kernel_launch(void* const* d_in, const int* in_sizes, int n_in,
                              void* d_out, int out_size, void* d_ws, size_t ws_size,
                              hipStream_t stream) {
    const float* x       = (const float*)d_in[0];
    const int*   packed  = (const int*)d_in[1];
    const float* scales  = (const float*)d_in[2];
    const float* offsets = (const float*)d_in[3];
    const float* bias    = (const float*)d_in[4];
    float* out = (float*)d_out;

    ushort* wb = (ushort*)d_ws;   // 4096*4096*2 = 32 MiB

    // 8,388,608 packed ints / 4 per thread / 256 per block
    dequant_kernel<<<8192, 256, 0, stream>>>(packed, scales, offsets, wb);

    dim3 grid(OUT_F / 128, M_TOT / 128);   // (32, 64)
    gemm_kernel<<<grid, 256, 0, stream>>>(x, wb, bias, out);
}